// Round 12
// baseline (486.411 us; speedup 1.0000x reference)
//
#include <hip/hip_runtime.h>
#include <hip/hip_bf16.h>

typedef __attribute__((ext_vector_type(8))) short short8v;
typedef __attribute__((ext_vector_type(4))) float f32x4;

#define W_  128
#define HW_ 16384

#define MFMA32(a, b, c) __builtin_amdgcn_mfma_f32_16x16x32_bf16(a, b, c, 0, 0, 0)

__device__ __forceinline__ short hb(float f) {
    __hip_bfloat16 b = __float2bfloat16(f);   // HW RNE convert (v_cvt_pk-fusable)
    return *reinterpret_cast<short*>(&b);
}

// LDS-FREE K-loop. 512 thr = 8 waves = 4 row-pair groups x 2 col-halves.
// Tile 8h x 16w, all 81 displacements. Wave (grp,nt): out rows {2grp,2grp+1},
// N-cols nt*16..nt*16+15 of the 32-col band -> acc[2][9] = 72 regs.
// B-frags are loaded DIRECTLY from global: lane (m,g) needs
// in2[c0+8g+i][row][w0-4+16nt+m] -- same 64B-coalesced shape as the A-load.
// No __syncthreads, no LDS, no lockstep anywhere in the K-loop: each wave
// free-runs; compiler pipelines loads arbitrarily deep (nothing fences it).
// Rounds 4-11 lesson: every LDS-staged variant pinned at ~100us with all
// pipes <30% busy -- the staging chain itself was the floor.
// Redundant in2/A reads (~2.5x) go through L2 (~20us of L2 BW, affordable).
// Epilogue: validated band->LDS(stride 132)->coalesced sweep, ONE barrier.
// NOTE: all acc indices compile-time constant (round-3 scratch-demotion lesson).
__global__ __launch_bounds__(512, 2)
void corr_kernel(const float* __restrict__ in1, const float* __restrict__ in2,
                 float* __restrict__ out)
{
    __shared__ float ldso[81 * 132];   // 42.8 KB, epilogue only

    const int tid  = threadIdx.x;
    const int lane = tid & 63;
    const int wid  = tid >> 6;     // 0..7
    const int grp  = wid >> 1;     // 0..3 row-pair group
    const int nt   = wid & 1;      // col half
    const int m    = lane & 15;    // M row / N col within 16x16
    const int g    = lane >> 4;    // k-octet

    // 1024 blocks; XCD = image (bid&7), w-tiles fastest for L2 reuse
    int bid = blockIdx.x;
    int n   = bid & 7;
    int k   = bid >> 3;            // 0..127
    int h0  = (k >> 3) << 3;       // 0,8,...,120
    int w0  = (k & 7) << 4;        // 0,16,...,112

    const float* in1n = in1 + (size_t)n * (256 * HW_);
    const float* in2n = in2 + (size_t)n * (256 * HW_);

    const int  colB  = w0 - 4 + 16 * nt + m;          // B column (global w)
    const bool colOK = ((unsigned)colB < 128u);
    const int  aoff0 = (8 * g) * HW_ + (h0 + 2 * grp) * W_ + (w0 + m);
    const int  boff0 = (8 * g) * HW_ + colB;

    f32x4 acc[2][9];
#pragma unroll
    for (int rs = 0; rs < 2; ++rs)
#pragma unroll
        for (int d = 0; d < 9; ++d)
            acc[rs][d] = (f32x4){0.f, 0.f, 0.f, 0.f};

    // ---- K loop: 8 chunks of 32 channels; pure load->cvt->MFMA, no fences ----
    for (int t = 0; t < 8; ++t) {
        const int c0 = 32 * t * HW_;

        // A-frags for both rows (64B-coalesced per 16-lane group)
        short8v a8[2];
#pragma unroll
        for (int rs = 0; rs < 2; ++rs) {
            float v[8];
#pragma unroll
            for (int i = 0; i < 8; ++i)
                v[i] = in1n[aoff0 + rs * W_ + c0 + i * HW_];
#pragma unroll
            for (int i = 0; i < 8; ++i) a8[rs][i] = hb(v[i]);
        }

        // B rows rr = rs+dy in 0..9; each feeds up to 2 acc rows (dedup)
#pragma unroll
        for (int rr = 0; rr < 10; ++rr) {
            const int rowr = h0 + 2 * grp - 4 + rr;
            short8v b = (short8v)0;
            if ((unsigned)rowr < 128u) {               // wave-uniform branch
                const int bb = boff0 + c0 + rowr * W_;
                float u[8];
#pragma unroll
                for (int i = 0; i < 8; ++i)
                    u[i] = colOK ? in2n[bb + i * HW_] : 0.f;
#pragma unroll
                for (int i = 0; i < 8; ++i) b[i] = hb(u[i]);
            }
            if (rr <= 8) acc[0][rr]     = MFMA32(a8[0], b, acc[0][rr]);
            if (rr >= 1) acc[1][rr - 1] = MFMA32(a8[1], b, acc[1][rr - 1]);
        }
    }

    // ---- epilogue: bands -> ldso (stride 132: 4*band%32 bank spread) ----
#pragma unroll
    for (int dy = 0; dy < 9; ++dy) {
#pragma unroll
        for (int rs = 0; rs < 2; ++rs) {
#pragma unroll
            for (int i = 0; i < 4; ++i) {
                int mm = 4 * g + i;                    // D row = pixel w offset
                int dx = 16 * nt + m - mm;             // D col = mm + dx
                if (dx >= 0 && dx < 9)
                    ldso[(dy * 9 + dx) * 132 + (2 * grp + rs) * 16 + mm] = acc[rs][dy][i];
            }
        }
    }
    __syncthreads();
    const size_t outb = (size_t)n * 81 * HW_;
#pragma unroll
    for (int e = 0; e < 21; ++e) {
        int t2 = tid + e * 512;
        if (t2 < 10368) {                              // 81 bands x 128 px
            int dydx = t2 >> 7;
            int rem  = t2 & 127;                       // row*16 + w
            out[outb + (size_t)dydx * HW_ +
                (size_t)(h0 + (rem >> 4)) * W_ + (w0 + (rem & 15))] = ldso[dydx * 132 + rem];
        }
    }
}

extern "C" void kernel_launch(void* const* d_in, const int* in_sizes, int n_in,
                              void* d_out, int out_size, void* d_ws, size_t ws_size,
                              hipStream_t stream) {
    const float* in1 = (const float*)d_in[0];
    const float* in2 = (const float*)d_in[1];
    float* out = (float*)d_out;
    corr_kernel<<<dim3(1024), dim3(512), 0, stream>>>(in1, in2, out);
}

// Round 13
// 160.853 us; speedup vs baseline: 3.0239x; 3.0239x over previous
//
#include <hip/hip_runtime.h>
#include <limits.h>

typedef __attribute__((ext_vector_type(8))) short short8v;
typedef __attribute__((ext_vector_type(4))) float f32x4;
typedef __attribute__((ext_vector_type(4))) unsigned u32x4;

#define W_  128
#define HW_ 16384

#define MFMA32(a, b, c) __builtin_amdgcn_mfma_f32_16x16x32_bf16(a, b, c, 0, 0, 0)

__device__ __forceinline__ unsigned bf16pk(float lo, float hi) {
    unsigned ul = __float_as_uint(lo);
    ul += 0x7fffu + ((ul >> 16) & 1u);
    unsigned uh = __float_as_uint(hi);
    uh += 0x7fffu + ((uh >> 16) & 1u);
    return (ul >> 16) | (uh & 0xffff0000u);
}

// 512 thr = 8 waves; tile 16h x 16w, all 81 disp; wave owns rows {2w,2w+1}.
// NO sched_barrier anywhere (round-13 ablation: r2-r11 pinned the schedule
// after every barrier -- the m141-class serializer; all pipes idle at ~100us).
// Ping-pong 2x48KB, ONE barrier per chunk:
//   loop t: issue loads t+1 -> barrier -> MFMA from buf[t&1] -> pack+write
//   buf[(t+1)&1]  (write-vs-read always different buffer; cross-iter hazards
//   ordered by the single barrier; vmcnt wait sits a full MFMA phase after issue)
// Staging: 576 units (r24 x j4 x cg6), f32x4 col loads (8 per unit) ->
// b128 writes (4 per unit) into [rj][col'32][k8] with rotation
// col' = (col + rj) & 31 on write AND read: b128 start slots spread over all
// 8 positions -> near-conflict-free (r6-r11's dword scatter ran 6-10M).
// Junk col region (rotated image of cols 24..31): never written real data,
// feeds only never-stored acc elements; finite/NaN garbage harmless.
// NOTE: all acc[][][] indices compile-time constant (round-3 lesson).
__global__ __launch_bounds__(512, 2)
void corr_kernel(const float* __restrict__ in1, const float* __restrict__ in2,
                 float* __restrict__ out)
{
    __shared__ __attribute__((aligned(16))) unsigned char smem[98304];
    short* lds  = (short*)smem;          // 2 x 24576 shorts ping-pong
    float* ldso = (float*)smem;          // epilogue view (81*257*4 = 83KB alias)

    const int tid  = threadIdx.x;
    const int lane = tid & 63;
    const int wid  = tid >> 6;        // 0..7
    const int m    = lane & 15;       // M row / N col in 16x16 tile
    const int g    = lane >> 4;       // k-octet 0..3

    int bid = blockIdx.x;
    int swz = (bid & 7) * 64 + (bid >> 3);       // bijective XCD swizzle; 1 image/XCD
    int n   = swz >> 6;
    int h0  = ((swz >> 3) & 7) << 4;
    int w0  = (swz & 7) << 4;

    const float* in1n = in1 + (size_t)n * (256 * HW_);
    const float* in2n = in2 + (size_t)n * (256 * HW_);

    // ---- staging geometry: unit u = rj*6 + cg, 576 units (s=1: tid<64) ----
    // unit: rj = r*4+j (r in2-row 0..23, j k-octet), cols 4cg..4cg+3, 8 channels.
    int gofs[2], wrow[2], wcp0[2];
    bool act[2];
#pragma unroll
    for (int s = 0; s < 2; ++s) {
        int u    = tid + s * 512;
        act[s]   = (u < 576);
        int cg   = u % 6;
        int rj   = u / 6;             // 0..95
        int r    = rj >> 2;
        int j    = rj & 3;
        int row  = h0 - 4 + r;
        int col0 = w0 - 4 + 4 * cg;
        bool inb = act[s] && ((unsigned)row < 128u) && ((unsigned)col0 < 125u);
        gofs[s]  = inb ? ((8 * j) * HW_ + row * W_ + col0) : INT_MIN;
        wrow[s]  = rj * 256;          // short offset of row base (32 cols x 8 k)
        wcp0[s]  = 4 * cg + rj;       // col' = (wcp0 + d) & 31
    }
    const int abase = (8 * g) * HW_ + (h0 + 2 * wid) * W_ + (w0 + m);

    f32x4 acc[2][9][2];
#pragma unroll
    for (int a = 0; a < 2; ++a)
#pragma unroll
        for (int d = 0; d < 9; ++d)
#pragma unroll
            for (int t = 0; t < 2; ++t)
                acc[a][d][t] = (f32x4){0.f, 0.f, 0.f, 0.f};

    // ---- prologue: load chunk 0, pack, write buf0 ----
    {
        f32x4 v[2][8];
        float af0[2][8];
#pragma unroll
        for (int s = 0; s < 2; ++s)
#pragma unroll
            for (int i = 0; i < 8; ++i) {
                f32x4 x = (f32x4){0.f, 0.f, 0.f, 0.f};
                if (gofs[s] != INT_MIN) x = *(const f32x4*)(in2n + gofs[s] + i * HW_);
                v[s][i] = x;
            }
#pragma unroll
        for (int rs = 0; rs < 2; ++rs)
#pragma unroll
            for (int i = 0; i < 8; ++i)
                af0[rs][i] = in1n[abase + rs * W_ + i * HW_];
#pragma unroll
        for (int s = 0; s < 2; ++s)
            if (act[s]) {
#pragma unroll
                for (int d = 0; d < 4; ++d) {
                    u32x4 pk;
#pragma unroll
                    for (int h = 0; h < 4; ++h)
                        pk[h] = bf16pk(v[s][2 * h][d], v[s][2 * h + 1][d]);
                    *(u32x4*)&lds[wrow[s] + ((wcp0[s] + d) & 31) * 8] = pk;
                }
            }
        // keep A floats for chunk 0 in af[] via fallthrough below
        // (store into the loop-carried array)
        // af is declared below; copy here
        // -- handled by declaring af before prologue instead:
        (void)0;
        // move af0 into loop-carried af
        // (see af declaration below)
        // NOTE: code structured so af is assigned here:
#pragma unroll
        for (int rs = 0; rs < 2; ++rs)
#pragma unroll
            for (int i = 0; i < 8; ++i)
                ; // placeholder (af assigned below)
        // real assignment done via af declared prior -- restructure:
        // (see next block)
        // To keep it simple, recompute a-pack now:
        // a-pack for chunk 0:
        // an[rs][h] = bf16pk(af0[rs][2h], af0[rs][2h+1])
        // stored in an[]:
        // (declared below)
        // -- we inline here:
        extern __shared__ unsigned char _dummy[]; (void)_dummy;
        // pack A chunk 0
        // an is declared just after; to allow assignment we declare it static-scope:
        // (handled: an declared before this block in final layout)
        // --- see below ---
        // (this comment block intentionally inert)
        // store:
        //   an[rs] = ...
        // fallthrough
        // (assignments below)
        //
        // Pack A now into anP (declared above main loop)
        //
        // (done after block)
        //
        // save af0 to anP:
        //
        // ---- end prologue loads ----
        __syncthreads();  // make buf0 visible before first MFMA
        // stash packed A in anP
        // (see below)
        // we pass af0 out via anP:
        // (assign)
        //
        // (note: barrier placed here is the t=0 loop barrier equivalent;
        //  loop below starts with loads for t+1, then uses buf0)
        //
        // Assign anP:
        //
        // final:
        //
        //
        // pack:
        //
        // (actual code)
        //
        // ---- begin main loop ----
        u32x4 anP[2];
#pragma unroll
        for (int rs = 0; rs < 2; ++rs) {
            u32x4 pk;
#pragma unroll
            for (int h = 0; h < 4; ++h)
                pk[h] = bf16pk(af0[rs][2 * h], af0[rs][2 * h + 1]);
            anP[rs] = pk;
        }

#pragma unroll 1
        for (int t = 0; t < 8; ++t) {
            // issue loads for chunk t+1 (free to hoist/sink: no sched pins)
            f32x4 vn[2][8];
            float afn[2][8];
            if (t < 7) {
                const int koff = (t + 1) * 32 * HW_;
#pragma unroll
                for (int s = 0; s < 2; ++s)
#pragma unroll
                    for (int i = 0; i < 8; ++i) {
                        f32x4 x = (f32x4){0.f, 0.f, 0.f, 0.f};
                        if (gofs[s] != INT_MIN)
                            x = *(const f32x4*)(in2n + gofs[s] + koff + i * HW_);
                        vn[s][i] = x;
                    }
#pragma unroll
                for (int rs = 0; rs < 2; ++rs)
#pragma unroll
                    for (int i = 0; i < 8; ++i)
                        afn[rs][i] = in1n[abase + koff + rs * W_ + i * HW_];
            }

            if (t > 0) __syncthreads();   // buf[t&1] writes visible (t=0: prologue barrier)

            // A frags for chunk t
            short8v a8[2];
#pragma unroll
            for (int rs = 0; rs < 2; ++rs) {
                u32x4 tmp = anP[rs];
                a8[rs] = *reinterpret_cast<short8v*>(&tmp);
            }

            // MFMA from buf[t&1]; rotated b128 reads; rr-dedup
            const short* lb = lds + (t & 1) * 24576;
#pragma unroll
            for (int rr = 0; rr < 10; ++rr) {
                int rj2 = (2 * wid + rr) * 4 + g;
                int ro  = rj2 * 256;
                short8v b0 = *(const short8v*)&lb[ro + ((m + rj2) & 31) * 8];
                short8v b1 = *(const short8v*)&lb[ro + ((16 + m + rj2) & 31) * 8];
                if (rr <= 8) {
                    acc[0][rr][0] = MFMA32(a8[0], b0, acc[0][rr][0]);
                    acc[0][rr][1] = MFMA32(a8[0], b1, acc[0][rr][1]);
                }
                if (rr >= 1) {
                    acc[1][rr - 1][0] = MFMA32(a8[1], b0, acc[1][rr - 1][0]);
                    acc[1][rr - 1][1] = MFMA32(a8[1], b1, acc[1][rr - 1][1]);
                }
            }

            // pack + write chunk t+1 into buf[(t+1)&1] (vmcnt wait lands here,
            // a full MFMA phase after issue; different buffer than reads)
            if (t < 7) {
                short* wb = lds + ((t + 1) & 1) * 24576;
#pragma unroll
                for (int s = 0; s < 2; ++s)
                    if (act[s]) {
#pragma unroll
                        for (int d = 0; d < 4; ++d) {
                            u32x4 pk;
#pragma unroll
                            for (int h = 0; h < 4; ++h)
                                pk[h] = bf16pk(vn[s][2 * h][d], vn[s][2 * h + 1][d]);
                            *(u32x4*)&wb[wrow[s] + ((wcp0[s] + d) & 31) * 8] = pk;
                        }
                    }
#pragma unroll
                for (int rs = 0; rs < 2; ++rs) {
                    u32x4 pk;
#pragma unroll
                    for (int h = 0; h < 4; ++h)
                        pk[h] = bf16pk(afn[rs][2 * h], afn[rs][2 * h + 1]);
                    anP[rs] = pk;
                }
            }
        }
    }

    // ---- epilogue: all 81 bands -> ldso (stride 257) -> coalesced stores ----
    __syncthreads();   // all MFMA reads of lds done before aliasing as ldso
#pragma unroll
    for (int dy = 0; dy < 9; ++dy) {
#pragma unroll
        for (int rs = 0; rs < 2; ++rs) {
#pragma unroll
            for (int nt = 0; nt < 2; ++nt) {
#pragma unroll
                for (int i = 0; i < 4; ++i) {
                    int mm = 4 * g + i;              // D row = pixel w offset
                    int dx = nt * 16 + m - mm;       // D col = mm + dx
                    if (dx >= 0 && dx < 9)
                        ldso[(dy * 9 + dx) * 257 + (2 * wid + rs) * 16 + mm] = acc[rs][dy][nt][i];
                }
            }
        }
    }
    __syncthreads();
    const size_t outb = (size_t)n * 81 * HW_;
#pragma unroll
    for (int e = 0; e < 41; ++e) {
        int t2 = tid + e * 512;
        if (t2 < 20736) {                            // 81 bands x 256 px
            int dydx = t2 >> 8;
            int rem  = t2 & 255;                     // row*16 + w
            out[outb + (size_t)dydx * HW_ +
                (size_t)(h0 + (rem >> 4)) * W_ + (w0 + (rem & 15))] = ldso[dydx * 257 + rem];
        }
    }
}

extern "C" void kernel_launch(void* const* d_in, const int* in_sizes, int n_in,
                              void* d_out, int out_size, void* d_ws, size_t ws_size,
                              hipStream_t stream) {
    const float* in1 = (const float*)d_in[0];
    const float* in2 = (const float*)d_in[1];
    float* out = (float*)d_out;
    corr_kernel<<<dim3(512), dim3(512), 0, stream>>>(in1, in2, out);
}

// Round 14
// 99.253 us; speedup vs baseline: 4.9007x; 1.6206x over previous
//
#include <hip/hip_runtime.h>
#include <hip/hip_bf16.h>
#include <limits.h>

typedef __attribute__((ext_vector_type(8))) short short8v;
typedef __attribute__((ext_vector_type(4))) short short4v;
typedef __attribute__((ext_vector_type(4))) float f32x4;

#define H_  128
#define W_  128
#define C_  256
#define HW_ 16384

#define MFMA32(a, b, c) __builtin_amdgcn_mfma_f32_16x16x32_bf16(a, b, c, 0, 0, 0)

__device__ __forceinline__ short bf16b(float f) {
    unsigned u = __float_as_uint(f);
    u += 0x7fffu + ((u >> 16) & 1u);   // round-to-nearest-even
    return (short)(u >> 16);
}

// 512 threads = 8 waves. Tile: 16h x 16w pixels, all 81 displacements.
// Wave w owns out rows {2w, 2w+1}. K in 32-channel chunks, ping-pong LDS.
// in2 staged with float4 col-loads and transposed to k-minor LDS
// [r][j][col32][8k] via 4x ds_write_b16 per unit.
// B-frag reads dedup'd over rr = rs+dy (20 instead of 36 ds_read_b128/wave).
// ROUND-14 ABLATION: identical to round 6 EXCEPT all sched_barrier(0) pins
// removed. r1 (the only pin-free timed kernel) replayed at ~35us; every
// pinned variant (r4-r11) replays at 98-110us with all pipes <30% busy --
// the m141-class order-pinning regression. __syncthreads() alone is a full
// source-level memory fence; the pins only forbid the compiler from hoisting
// next-chunk loads into the MFMA stream.
// NOTE: all acc[][][] indices compile-time constant (round-3 lesson: one
// runtime index demotes acc to scratch -> 1.37GB spill writes).
__global__ __launch_bounds__(512, 2)
void corr_kernel(const float* __restrict__ in1, const float* __restrict__ in2,
                 float* __restrict__ out)
{
    __shared__ short lds2[2][24 * 4 * 32 * 8];   // 2 x 48 KiB ping-pong
    __shared__ float ldso[9 * 257];              // epilogue band->coalesced staging

    const int tid  = threadIdx.x;
    const int lane = tid & 63;
    const int wid  = tid >> 6;        // 0..7
    const int m    = lane & 15;       // M row / N col in 16x16 tile
    const int g    = lane >> 4;       // k-octet 0..3

    int bid = blockIdx.x;
    int swz = (bid & 7) * 64 + (bid >> 3);       // bijective XCD swizzle; 1 image/XCD
    int n   = swz >> 6;
    int h0  = ((swz >> 3) & 7) << 4;
    int w0  = (swz & 7) << 4;

    const float* in1n = in1 + (size_t)n * (C_ * HW_);
    const float* in2n = in2 + (size_t)n * (C_ * HW_);

    // ---- chunk-invariant stage geometry ----
    // f4-unit u: q=col-group(0..5, c0=4q), i=k-in-octet(0..7), j=k-octet(0..3), r=row(0..23)
    // 24*4*8*6 = 4608 units = 9 * 512 exactly.
    int lwoff[9]; int gofs[9];
#pragma unroll
    for (int s = 0; s < 9; ++s) {
        int u    = tid + s * 512;
        int q    = u % 6;
        int rest = u / 6;             // 0..767
        int i    = rest & 7;
        int rj   = rest >> 3;         // 0..95
        int j    = rj & 3;
        int r    = rj >> 2;           // 0..23
        int row  = h0 - 4 + r;
        int col0 = w0 - 4 + 4 * q;
        bool inb = ((unsigned)row < 128u) && ((unsigned)col0 < 125u);
        gofs[s]  = inb ? ((j * 8 + i) * HW_ + row * W_ + col0) : INT_MIN;
        lwoff[s] = ((r * 4 + j) * 32 + 4 * q) * 8 + i;
    }
    const int abase = (8 * g) * HW_ + (h0 + 2 * wid) * W_ + (w0 + m);

    // ---- zero both LDS buffers (cols 24..31 must read as 0) ----
    {
        short8v z = (short8v)0;
        short8v* zp = (short8v*)&lds2[0][0];
#pragma unroll
        for (int i = 0; i < 12; ++i) zp[tid + i * 512] = z;
    }
    __syncthreads();

    f32x4 acc[2][9][2];
#pragma unroll
    for (int a = 0; a < 2; ++a)
#pragma unroll
        for (int d = 0; d < 9; ++d)
#pragma unroll
            for (int t = 0; t < 2; ++t)
                acc[a][d][t] = (f32x4){0.f, 0.f, 0.f, 0.f};

    // ---- prologue: stage chunk 0 into buf 0 ----
    {
        f32x4 sv[9];
#pragma unroll
        for (int s = 0; s < 9; ++s) {
            f32x4 v = (f32x4){0.f, 0.f, 0.f, 0.f};
            if (gofs[s] != INT_MIN) v = *(const f32x4*)(in2n + gofs[s]);
            sv[s] = v;
        }
#pragma unroll
        for (int s = 0; s < 9; ++s) {
            short* p = &lds2[0][lwoff[s]];
#pragma unroll
            for (int d = 0; d < 4; ++d) p[8 * d] = bf16b(sv[s][d]);
        }
    }

    // ---- main loop: 8 chunks of 32 channels, ping-pong; stage t+1 overlaps MFMA t ----
#pragma unroll 1
    for (int t = 0; t < 8; ++t) {
        __syncthreads();
        const int rb = t & 1;

        // A loads for chunk t (issued first so their vmcnt drains first)
        float af[2][8];
#pragma unroll
        for (int rs = 0; rs < 2; ++rs)
#pragma unroll
            for (int i = 0; i < 8; ++i)
                af[rs][i] = in1n[abase + (32 * t + i) * HW_ + rs * W_];

        // in2 float4 loads for chunk t+1 (latency hidden under MFMA below)
        f32x4 sv[9];
        if (t < 7) {
            const int koff = (t + 1) * 32 * HW_;
#pragma unroll
            for (int s = 0; s < 9; ++s) {
                f32x4 v = (f32x4){0.f, 0.f, 0.f, 0.f};
                if (gofs[s] != INT_MIN) v = *(const f32x4*)(in2n + gofs[s] + koff);
                sv[s] = v;
            }
        }

        short8v a8[2];
#pragma unroll
        for (int rs = 0; rs < 2; ++rs)
#pragma unroll
            for (int i = 0; i < 8; ++i) a8[rs][i] = bf16b(af[rs][i]);

        // MFMA, dedup'd over rr = rs+dy: B row 2wid+rr read once, used by up to 2 acc rows
        const short* lb = &lds2[rb][0];
#pragma unroll
        for (int rr = 0; rr < 10; ++rr) {
            int ro = (((2 * wid + rr) * 4 + g) * 32) * 8;
            short8v b0 = *(const short8v*)&lb[ro + m * 8];
            short8v b1 = *(const short8v*)&lb[ro + (16 + m) * 8];
            if (rr <= 8) {
                acc[0][rr][0] = MFMA32(a8[0], b0, acc[0][rr][0]);
                acc[0][rr][1] = MFMA32(a8[0], b1, acc[0][rr][1]);
            }
            if (rr >= 1) {
                acc[1][rr - 1][0] = MFMA32(a8[1], b0, acc[1][rr - 1][0]);
                acc[1][rr - 1][1] = MFMA32(a8[1], b1, acc[1][rr - 1][1]);
            }
        }

        // transpose-scatter staged chunk t+1 into the other buffer (4 x b16 per unit)
        if (t < 7) {
#pragma unroll
            for (int s = 0; s < 9; ++s) {
                short* p = &lds2[rb ^ 1][lwoff[s]];
#pragma unroll
                for (int d = 0; d < 4; ++d) p[8 * d] = bf16b(sv[s][d]);
            }
        }
    }

    // ---- epilogue: band -> ldso (stride 257) -> coalesced 64B stores ----
    // FULLY unrolled over dy: acc indices stay compile-time constants.
    const size_t outb = (size_t)n * 81 * HW_;
#pragma unroll
    for (int dy = 0; dy < 9; ++dy) {
        __syncthreads();
#pragma unroll
        for (int rs = 0; rs < 2; ++rs) {
            int hl = 2 * wid + rs;
#pragma unroll
            for (int nt = 0; nt < 2; ++nt) {
#pragma unroll
                for (int i = 0; i < 4; ++i) {
                    int mm = 4 * g + i;              // D row = pixel w offset
                    int dx = nt * 16 + m - mm;       // D col = mm + dx
                    if (dx >= 0 && dx < 9)
                        ldso[dx * 257 + hl * 16 + mm] = acc[rs][dy][nt][i];
                }
            }
        }
        __syncthreads();
#pragma unroll
        for (int e = 0; e < 5; ++e) {
            int t = tid + e * 512;
            if (t < 2304) {
                int dx  = t >> 8;
                int rem = t & 255;                   // hl*16 + w
                out[outb + (size_t)(dy * 9 + dx) * HW_ +
                    (size_t)(h0 + (rem >> 4)) * W_ + (w0 + (rem & 15))] = ldso[dx * 257 + rem];
            }
        }
    }
}

extern "C" void kernel_launch(void* const* d_in, const int* in_sizes, int n_in,
                              void* d_out, int out_size, void* d_ws, size_t ws_size,
                              hipStream_t stream) {
    const float* in1 = (const float*)d_in[0];
    const float* in2 = (const float*)d_in[1];
    float* out = (float*)d_out;
    corr_kernel<<<dim3(512), dim3(512), 0, stream>>>(in1, in2, out);
}